// Round 13
// baseline (333.481 us; speedup 1.0000x reference)
//
#include <hip/hip_runtime.h>

#define NPRI 21504
#define BATCH 64
#define KTOP 1024
#define NBIN 16384
#define CAND 2048

typedef unsigned long long u64;
typedef unsigned int u32;

// correctly-rounded f32 exp via f64 libm exp (validated: absmax 3e-8)
__device__ __forceinline__ float crexpf(float x) { return (float)exp((double)x); }

__device__ __forceinline__ u64 readlane64(u64 v, int lane) {
  int lo = __builtin_amdgcn_readlane((int)(u32)v, lane);
  int hi = __builtin_amdgcn_readlane((int)(u32)(v >> 32), lane);
  return ((u64)(u32)hi << 32) | (u64)(u32)lo;
}

// Key packing: score>0 so f32 bits are order-monotone. NPRI-1-idx < 2^15.
// Descending u64 order == (score desc, idx asc) == lax.top_k stable order.
// Keys are UNIQUE => the top-1024 set and its desc order are unique, so any
// correct selection structure is bit-exact vs the validated sort+merge.

// K0: zero the histogram (kernel, not memset — graph-capture safe by construction)
__global__ __launch_bounds__(256) void k_zero(u32* __restrict__ p, int n) {
  int t = blockIdx.x * 256 + threadIdx.x;
  if (t < n) p[t] = 0;
}

// K1: f32-stepwise softmax score (validated) -> key -> global store + histogram.
// Bin = top 14 bits of score_bits (= key >> 33).
__global__ __launch_bounds__(256) void k_key(const float* __restrict__ confs,
                                             u64* __restrict__ keyG,
                                             u32* __restrict__ hist) {
  int t = blockIdx.x * 256 + threadIdx.x;
  if (t >= BATCH * NPRI) return;
  int b = t / NPRI;
  int n = t - b * NPRI;
  float2 v = ((const float2*)confs)[t];
  float m = fmaxf(v.x, v.y);
  float e0 = crexpf(v.x - m);
  float e1 = crexpf(v.y - m);
  float s = e1 / (e0 + e1);            // exact f32 steps (validated)
  u64 key = ((u64)__float_as_uint(s) << 15) | (u64)(NPRI - 1 - n);
  keyG[t] = key;
  atomicAdd(&hist[(size_t)b * NBIN + (u32)(key >> 33)], 1u);
}

// K2: per image: find threshold bin H (rank-1024 crossing) from the histogram,
// compact all keys with bin >= H (~1.3k), bitonic-sort 2048 desc (validated
// network), decode top-1024 (validated round-7 expressions) + valid-ballot.
__global__ __launch_bounds__(256) void k_sel(const u64* __restrict__ keyG,
                                             const u32* __restrict__ hist,
                                             const float* __restrict__ locs,
                                             const float* __restrict__ priors,
                                             float* __restrict__ boxF,
                                             float* __restrict__ scoreF,
                                             u64* __restrict__ validW) {
  const int b = blockIdx.x;
  const int t = threadIdx.x;
  __shared__ u32 seg[256];
  __shared__ u32 suf[256];
  __shared__ u32 sH, sCnt;
  __shared__ u64 cand[CAND];
  const u32* Hh = hist + (size_t)b * NBIN;
  // segment sums (thread t owns bins [t*64, t*64+64))
  u32 acc = 0;
  for (int k = 0; k < NBIN / 256; k++) acc += Hh[t * (NBIN / 256) + k];
  seg[t] = acc;
  suf[t] = acc;
  if (t == 0) sCnt = 0;
  __syncthreads();
  // inclusive suffix sum over segments (Hillis-Steele)
  for (int s = 1; s < 256; s <<= 1) {
    u32 v = (t + s < 256) ? suf[t + s] : 0;
    __syncthreads();
    suf[t] += v;
    __syncthreads();
  }
  // rank-1024 crossing: unique thread whose segment contains it walks top-down
  {
    u32 run = suf[t] - seg[t];             // keys in higher segments
    if (run < KTOP && suf[t] >= KTOP) {
      for (int k = NBIN / 256 - 1; k >= 0; k--) {
        u32 c = Hh[t * (NBIN / 256) + k];
        if (run < KTOP && run + c >= KTOP) sH = (u32)(t * (NBIN / 256) + k);
        run += c;
      }
    }
  }
  for (int k = t; k < CAND; k += 256) cand[k] = 0;
  __syncthreads();
  const u32 thrH = sH;
  // compact candidates (bin >= thrH): superset of the true top-1024
  const u64* kg = keyG + (size_t)b * NPRI;
  for (int k = 0; k < NPRI / 256; k++) {
    u64 key = kg[k * 256 + t];
    if ((u32)(key >> 33) >= thrH) {
      u32 p = atomicAdd(&sCnt, 1u);
      if (p < CAND) cand[p] = key;
    }
  }
  __syncthreads();
  // bitonic sort 2048 desc (validated network; zero-pad sinks to bottom)
  for (int kk = 2; kk <= CAND; kk <<= 1) {
    for (int j = kk >> 1; j > 0; j >>= 1) {
      __syncthreads();
      for (int l = t; l < CAND; l += 256) {
        int p = l ^ j;
        if (p > l) {
          u64 a = cand[l], q = cand[p];
          bool up = ((l & kk) == 0);
          if ((a > q) != up) { cand[l] = q; cand[p] = a; }
        }
      }
    }
  }
  __syncthreads();
  // decode top-1024: f32-stepwise (identical expressions to validated round 7)
  for (int i = t; i < KTOP; i += 256) {
    u64 K = cand[i];
    float sv = __uint_as_float((u32)(K >> 15));
    int idx = NPRI - 1 - (int)(K & 0x7FFFu);
    float4 lo = ((const float4*)locs)[(size_t)b * NPRI + idx];
    float4 pr = ((const float4*)priors)[idx];
    float cx = pr.x + (lo.x * 0.1f) * pr.z;
    float cy = pr.y + (lo.y * 0.1f) * pr.w;
    float w  = pr.z * crexpf(lo.z * 0.2f);
    float h  = pr.w * crexpf(lo.w * 0.2f);
    float x1 = cx - w * 0.5f;
    float y1 = cy - h * 0.5f;
    float x2 = x1 + w;
    float y2 = y1 + h;
    size_t o = (size_t)b * KTOP + i;
    boxF[o * 4 + 0] = x1;
    boxF[o * 4 + 1] = y1;
    boxF[o * 4 + 2] = x2;
    boxF[o * 4 + 3] = y2;
    scoreF[o] = sv;
    u64 mask = __ballot(sv > 0.5f);       // wave covers group i>>6
    if ((t & 63) == 0) validW[(size_t)b * 16 + (i >> 6)] = mask;
  }
}

// K3: upper-triangle suppression bitmask, load-balanced. Task = (row group g,
// 4-word chunk c). 40 equal tasks/image. Wave v owns word w = g+4c+v (wave-
// uniform => broadcast LDS reads, conflict-free — validated round 11/12).
// Words w<g never written nor read (k_scan only touches w>=g).
__global__ __launch_bounds__(256) void k_iou(const float* __restrict__ boxF,
                                             u64* __restrict__ sup) {
  const int b = blockIdx.y;
  int task = blockIdx.x;               // 0..39
  int g = 0, base = 0;
  for (int gg = 0; gg < 16; gg++) {
    int cg = (16 - gg + 3) >> 2;
    if (task < base + cg) { g = gg; break; }
    base += cg;
  }
  const int c = task - base;
  const int w0 = g + 4 * c;            // first word of this chunk
  __shared__ float4 BXS[256];
  __shared__ float ARS[256];
  const float4* bb = (const float4*)(boxF + (size_t)b * KTOP * 4);
  {
    int j = w0 * 64 + threadIdx.x;
    if (j < KTOP) {
      float4 v = bb[j];
      BXS[threadIdx.x] = v;
      ARS[threadIdx.x] = fmaxf(v.z - v.x, 0.0f) * fmaxf(v.w - v.y, 0.0f);
    }
  }
  const int r = threadIdx.x & 63;
  const int v = threadIdx.x >> 6;      // wave 0..3
  const int i = g * 64 + r;
  float4 bi = bb[i];
  float a = fmaxf(bi.z - bi.x, 0.0f) * fmaxf(bi.w - bi.y, 0.0f);
  __syncthreads();
  const int w = w0 + v;
  if (w < 16) {
    u64 word = 0;
    const int lbase = v * 64;
    for (int jb = 0; jb < 64; jb++) {
      int lj = lbase + jb;
      float4 bj = BXS[lj];             // broadcast (w uniform in wave)
      float aj = ARS[lj];
      float lx = fmaxf(bi.x, bj.x);
      float ly = fmaxf(bi.y, bj.y);
      float rx = fminf(bi.z, bj.z);
      float ry = fminf(bi.w, bj.w);
      float iw = fmaxf(rx - lx, 0.0f);
      float ih = fmaxf(ry - ly, 0.0f);
      float inter = iw * ih;
      float uni = (a + aj) - inter;
      float iou = inter / fmaxf(uni, 1e-9f);
      if (iou > 0.4f) word |= (1ULL << jb);
    }
    if (w == g) word &= (r == 63) ? 0ULL : (~0ULL << (r + 1));   // j > i
    sup[((size_t)b * KTOP + i) * 16 + w] = word;
  }
}

// K4: group-synchronous greedy NMS (validated round 12): ctz+readlane chain
// over kept bits only + register prefetch double-buffer. Exact greedy semantics.
__global__ __launch_bounds__(256) void k_scan(const u64* __restrict__ sup,
                                              const u64* __restrict__ validW,
                                              const float* __restrict__ boxF,
                                              const float* __restrict__ scoreF,
                                              float* __restrict__ out) {
  const int b = blockIdx.x;
  const int t = threadIdx.x;
  __shared__ u64 rows[2][64][16];      // 16 KB double buffer
  __shared__ u64 remv[16];
  __shared__ u64 keepW[16];
  __shared__ u64 vW[16];
  const u64* supB = sup + (size_t)b * KTOP * 16;
  for (int l = t; l < 1024; l += 256)
    rows[0][l >> 4][l & 15] = supB[l];
  if (t < 16) { remv[t] = 0; vW[t] = validW[(size_t)b * 16 + t]; }
  __syncthreads();
  for (int g = 0; g < 16; g++) {
    const int cur = g & 1;
    u64 pf0, pf1, pf2, pf3;
    if (g < 15) {
      const u64* nsrc = supB + (size_t)(g + 1) * 1024;
      pf0 = nsrc[t];
      pf1 = nsrc[t + 256];
      pf2 = nsrc[t + 512];
      pf3 = nsrc[t + 768];
    }
    if (t < 64) {
      u64 diag = rows[cur][t][g];        // lane i: row i's intra-group word
      u64 alive = vW[g] & ~remv[g];      // wave-uniform
      u64 keep = 0;
      u64 m = alive;
      while (m) {
        int i = __builtin_ctzll(m);
        keep |= (1ULL << i);
        u64 row = readlane64(diag, i);   // row i has only bits j>i
        alive &= ~row;
        m = (i == 63) ? 0ULL : (alive & (~0ULL << (i + 1)));
      }
      if (t == 0) keepW[g] = keep;
    }
    __syncthreads();
    {
      u64 kw = keepW[g];
      int w = t & 15;
      if (w > g) {
        int i0 = (t >> 4) * 4;
        u64 acc = 0;
        for (int i = i0; i < i0 + 4; i++)
          if ((kw >> i) & 1ULL) acc |= rows[cur][i][w];
        if (acc) atomicOr(&remv[w], acc);
      }
    }
    if (g < 15) {
      u64* dstb = &rows[cur ^ 1][0][0];
      dstb[t] = pf0;
      dstb[t + 256] = pf1;
      dstb[t + 512] = pf2;
      dstb[t + 768] = pf3;
    }
    __syncthreads();   // remv + next buffer visible
  }
  const float* bb = boxF + (size_t)b * KTOP * 4;
  const float* sc = scoreF + (size_t)b * KTOP;
  for (int i = t; i < KTOP; i += 256) {
    float kf = ((keepW[i >> 6] >> (i & 63)) & 1ULL) ? 1.0f : 0.0f;
    size_t o5 = ((size_t)b * KTOP + i) * 5;
    out[o5 + 0] = bb[i * 4 + 0] * kf;
    out[o5 + 1] = bb[i * 4 + 1] * kf;
    out[o5 + 2] = bb[i * 4 + 2] * kf;
    out[o5 + 3] = bb[i * 4 + 3] * kf;
    out[o5 + 4] = sc[i] * kf;
    out[(size_t)BATCH * KTOP * 5 + (size_t)b * KTOP + i] = kf;
  }
}

extern "C" void kernel_launch(void* const* d_in, const int* in_sizes, int n_in,
                              void* d_out, int out_size, void* d_ws, size_t ws_size,
                              hipStream_t stream) {
  const float* locs = nullptr;
  const float* confs = nullptr;
  const float* priors = nullptr;
  for (int i = 0; i < n_in; i++) {
    if (in_sizes[i] == BATCH * NPRI * 4) locs = (const float*)d_in[i];
    else if (in_sizes[i] == BATCH * NPRI * 2) confs = (const float*)d_in[i];
    else if (in_sizes[i] == NPRI * 4) priors = (const float*)d_in[i];
  }
  float* out = (float*)d_out;   // f32: [B,K,5] dets ++ [B,K] keep

  char* ws = (char*)d_ws;
  size_t off = 0;
  u64* keyG = (u64*)(ws + off);          // B*N*8 = 11,010,048
  u64* sup = (u64*)(ws + off);           // alias: keyG dead after k_sel (needs 8,388,608)
  off += (size_t)BATCH * NPRI * 8;
  u32* hist = (u32*)(ws + off);          off += (size_t)BATCH * NBIN * 4;       // 4,194,304
  float* boxF = (float*)(ws + off);      off += (size_t)BATCH * KTOP * 4 * 4;   // 1,048,576
  float* scoreF = (float*)(ws + off);    off += (size_t)BATCH * KTOP * 4;       //   262,144
  u64* validW = (u64*)(ws + off);        off += (size_t)BATCH * 16 * 8;         //     8,192
  // total ~16.5 MB

  const int histN = BATCH * NBIN;
  k_zero<<<(histN + 255) / 256, 256, 0, stream>>>(hist, histN);
  k_key<<<(BATCH * NPRI) / 256, 256, 0, stream>>>(confs, keyG, hist);
  k_sel<<<BATCH, 256, 0, stream>>>(keyG, hist, locs, priors, boxF, scoreF, validW);
  k_iou<<<dim3(40, BATCH), 256, 0, stream>>>(boxF, sup);
  k_scan<<<BATCH, 256, 0, stream>>>(sup, validW, boxF, scoreF, out);
}

// Round 15
// 332.345 us; speedup vs baseline: 1.0034x; 1.0034x over previous
//
#include <hip/hip_runtime.h>

#define NPRI 21504
#define BATCH 64
#define KTOP 1024
#define NBIN 16384
#define CAND 2048
#define NB (NPRI / 256)            // 84 chunks of 256 anchors
#define HF(x) ((x) + ((x) >> 6))   // pad 1 per 64: segment walk conflict-light

typedef unsigned long long u64;
typedef unsigned int u32;
typedef unsigned short u16;

// correctly-rounded f32 exp via f64 libm exp (validated: absmax 3e-8)
__device__ __forceinline__ float crexpf(float x) { return (float)exp((double)x); }

__device__ __forceinline__ u64 readlane64(u64 v, int lane) {
  int lo = __builtin_amdgcn_readlane((int)(u32)v, lane);
  int hi = __builtin_amdgcn_readlane((int)(u32)(v >> 32), lane);
  return ((u64)(u32)hi << 32) | (u64)(u32)lo;
}

// Key packing (validated): key = (score_bits << 15) | (NPRI-1-idx). Unique keys;
// desc order == (score desc, idx asc) == lax.top_k stable order. bin = key>>33
// = score_bits>>18 (top 14 bits).

// K0: zero histograms
__global__ __launch_bounds__(256) void k_zero(u32* __restrict__ p, int n) {
  int t = blockIdx.x * 256 + threadIdx.x;
  if (t < n) p[t] = 0;
}

// K1: f32-stepwise softmax score (validated) -> bin store (u16) + histogram.
__global__ __launch_bounds__(256) void k_hist(const float* __restrict__ confs,
                                              u16* __restrict__ binG,
                                              u32* __restrict__ hist) {
  int t = blockIdx.x * 256 + threadIdx.x;
  if (t >= BATCH * NPRI) return;
  int b = t / NPRI;
  float2 v = ((const float2*)confs)[t];
  float m = fmaxf(v.x, v.y);
  float e0 = crexpf(v.x - m);
  float e1 = crexpf(v.y - m);
  float s = e1 / (e0 + e1);            // exact f32 steps (validated)
  u32 bin = __float_as_uint(s) >> 18;  // top 14 bits == key>>33
  binG[t] = (u16)bin;
  atomicAdd(&hist[(size_t)b * NBIN + bin], 1u);
}

// K2: per image: threshold bin from histogram (u16 LDS, coalesced load),
// compact winner indices from u16 bins (tail-guarded batches), recompute winner
// keys in parallel, bitonic-2048 sort (validated), decode (validated).
// Static LDS ~55.8 KB (< 64 KB).
__global__ __launch_bounds__(256) void k_sel(const u16* __restrict__ binG,
                                             const u32* __restrict__ hist,
                                             const float* __restrict__ confs,
                                             const float* __restrict__ locs,
                                             const float* __restrict__ priors,
                                             float* __restrict__ boxF,
                                             float* __restrict__ scoreF,
                                             u64* __restrict__ validW) {
  const int b = blockIdx.x;
  const int t = threadIdx.x;
  __shared__ u16 histL[NBIN + (NBIN >> 6)];   // 33,280 B (counts <= 21504 fit u16)
  __shared__ u64 cand[CAND];                  // 16,384 B
  __shared__ u16 widx[CAND];                  // 4,096 B (indices < 21504 fit u16)
  __shared__ u32 seg[256];
  __shared__ u32 suf[256];
  __shared__ u32 sH, sCnt;
  const u32* Hh = hist + (size_t)b * NBIN;
  for (int l = t; l < NBIN; l += 256) histL[HF(l)] = (u16)Hh[l];   // coalesced
  if (t == 0) sCnt = 0;
  __syncthreads();
  // segment sums: thread t owns bins [t*64, t*64+64)
  {
    u32 acc = 0;
    const int s0 = t * 64;
    for (int k = 0; k < 64; k++) acc += (u32)histL[HF(s0 + k)];
    seg[t] = acc;
    suf[t] = acc;
  }
  __syncthreads();
  // inclusive suffix sum over segments (Hillis-Steele, validated)
  for (int s = 1; s < 256; s <<= 1) {
    u32 v = (t + s < 256) ? suf[t + s] : 0;
    __syncthreads();
    suf[t] += v;
    __syncthreads();
  }
  // rank-1024 crossing: unique owning thread walks its segment top-down
  {
    u32 run = suf[t] - seg[t];
    if (run < KTOP && suf[t] >= KTOP) {
      const int s0 = t * 64;
      for (int k = 63; k >= 0; k--) {
        u32 c = (u32)histL[HF(s0 + k)];
        if (run < KTOP && run + c >= KTOP) sH = (u32)(s0 + k);
        run += c;
      }
    }
  }
  __syncthreads();
  const u32 thrH = sH;
  // phase 1: compact winner indices (bin >= thrH) — tail-GUARDED batches
  const u16* bg = binG + (size_t)b * NPRI;
  for (int k0 = 0; k0 < NB; k0 += 8) {
    u16 bv[8];
    #pragma unroll
    for (int kb = 0; kb < 8; kb++) {
      int kk = k0 + kb;
      bv[kb] = (kk < NB) ? bg[kk * 256 + t] : (u16)0;
    }
    #pragma unroll
    for (int kb = 0; kb < 8; kb++) {
      int kk = k0 + kb;
      if (kk < NB && (u32)bv[kb] >= thrH) {
        u32 p = atomicAdd(&sCnt, 1u);
        if (p < CAND) widx[p] = (u16)(kk * 256 + t);
      }
    }
  }
  __syncthreads();
  const u32 nw = (sCnt < CAND) ? sCnt : CAND;
  // phase 2: recompute winner keys in parallel (bit-identical fp ops)
  const float2* cf = (const float2*)confs + (size_t)b * NPRI;
  for (int w = t; w < CAND; w += 256) {
    u64 key = 0;
    if (w < (int)nw) {
      u32 n = (u32)widx[w];
      float2 v = cf[n];
      float m = fmaxf(v.x, v.y);
      float e0 = crexpf(v.x - m);
      float e1 = crexpf(v.y - m);
      float s = e1 / (e0 + e1);
      key = ((u64)__float_as_uint(s) << 15) | (u64)(NPRI - 1 - n);
    }
    cand[w] = key;
  }
  // bitonic sort 2048 desc (validated network; zero-pad sinks to bottom)
  for (int kk = 2; kk <= CAND; kk <<= 1) {
    for (int j = kk >> 1; j > 0; j >>= 1) {
      __syncthreads();
      for (int l = t; l < CAND; l += 256) {
        int p = l ^ j;
        if (p > l) {
          u64 a = cand[l], q = cand[p];
          bool up = ((l & kk) == 0);
          if ((a > q) != up) { cand[l] = q; cand[p] = a; }
        }
      }
    }
  }
  __syncthreads();
  // decode top-1024: f32-stepwise (identical expressions to validated round 7)
  for (int i = t; i < KTOP; i += 256) {
    u64 K = cand[i];
    float sv = __uint_as_float((u32)(K >> 15));
    int idx = NPRI - 1 - (int)(K & 0x7FFFu);
    float4 lo = ((const float4*)locs)[(size_t)b * NPRI + idx];
    float4 pr = ((const float4*)priors)[idx];
    float cx = pr.x + (lo.x * 0.1f) * pr.z;
    float cy = pr.y + (lo.y * 0.1f) * pr.w;
    float w  = pr.z * crexpf(lo.z * 0.2f);
    float h  = pr.w * crexpf(lo.w * 0.2f);
    float x1 = cx - w * 0.5f;
    float y1 = cy - h * 0.5f;
    float x2 = x1 + w;
    float y2 = y1 + h;
    size_t o = (size_t)b * KTOP + i;
    boxF[o * 4 + 0] = x1;
    boxF[o * 4 + 1] = y1;
    boxF[o * 4 + 2] = x2;
    boxF[o * 4 + 3] = y2;
    scoreF[o] = sv;
    u64 mask = __ballot(sv > 0.5f);       // wave covers group i>>6
    if ((t & 63) == 0) validW[(size_t)b * 16 + (i >> 6)] = mask;
  }
}

// K3: upper-triangle suppression bitmask, broadcast-friendly mapping
// (r12-validated 16-block version: wave-uniform word => conflict-free).
__global__ __launch_bounds__(256) void k_iou(const float* __restrict__ boxF,
                                             u64* __restrict__ sup) {
  const int b = blockIdx.y;
  const int g = blockIdx.x;            // row group 0..15
  __shared__ float4 BXS[KTOP];
  __shared__ float ARS[KTOP];
  const float4* bb = (const float4*)(boxF + (size_t)b * KTOP * 4);
  for (int l = g * 64 + threadIdx.x; l < KTOP; l += 256) {
    float4 v = bb[l];
    BXS[l] = v;
    ARS[l] = fmaxf(v.z - v.x, 0.0f) * fmaxf(v.w - v.y, 0.0f);
  }
  __syncthreads();
  const int r = threadIdx.x & 63;
  const int v = threadIdx.x >> 6;      // wave 0..3
  const int i = g * 64 + r;
  const float4 bi = BXS[i];
  const float a = ARS[i];
  for (int w = g + v; w < 16; w += 4) {
    u64 word = 0;
    const int jbase = w * 64;
    for (int jb = 0; jb < 64; jb++) {
      int j = jbase + jb;
      float4 bj = BXS[j];              // broadcast (w uniform in wave)
      float aj = ARS[j];
      float lx = fmaxf(bi.x, bj.x);
      float ly = fmaxf(bi.y, bj.y);
      float rx = fminf(bi.z, bj.z);
      float ry = fminf(bi.w, bj.w);
      float iw = fmaxf(rx - lx, 0.0f);
      float ih = fmaxf(ry - ly, 0.0f);
      float inter = iw * ih;
      float uni = (a + aj) - inter;
      float iou = inter / fmaxf(uni, 1e-9f);
      if (iou > 0.4f) word |= (1ULL << jb);
    }
    if (w == g) word &= (r == 63) ? 0ULL : (~0ULL << (r + 1));   // j > i
    sup[((size_t)b * KTOP + i) * 16 + w] = word;
  }
}

// K4: group-synchronous greedy NMS (validated round 12): ctz+readlane chain
// over kept bits only + register prefetch double-buffer. Exact greedy semantics.
__global__ __launch_bounds__(256) void k_scan(const u64* __restrict__ sup,
                                              const u64* __restrict__ validW,
                                              const float* __restrict__ boxF,
                                              const float* __restrict__ scoreF,
                                              float* __restrict__ out) {
  const int b = blockIdx.x;
  const int t = threadIdx.x;
  __shared__ u64 rows[2][64][16];      // 16 KB double buffer
  __shared__ u64 remv[16];
  __shared__ u64 keepW[16];
  __shared__ u64 vW[16];
  const u64* supB = sup + (size_t)b * KTOP * 16;
  for (int l = t; l < 1024; l += 256)
    rows[0][l >> 4][l & 15] = supB[l];
  if (t < 16) { remv[t] = 0; vW[t] = validW[(size_t)b * 16 + t]; }
  __syncthreads();
  for (int g = 0; g < 16; g++) {
    const int cur = g & 1;
    u64 pf0, pf1, pf2, pf3;
    if (g < 15) {
      const u64* nsrc = supB + (size_t)(g + 1) * 1024;
      pf0 = nsrc[t];
      pf1 = nsrc[t + 256];
      pf2 = nsrc[t + 512];
      pf3 = nsrc[t + 768];
    }
    if (t < 64) {
      u64 diag = rows[cur][t][g];        // lane i: row i's intra-group word
      u64 alive = vW[g] & ~remv[g];      // wave-uniform
      u64 keep = 0;
      u64 m = alive;
      while (m) {
        int i = __builtin_ctzll(m);
        keep |= (1ULL << i);
        u64 row = readlane64(diag, i);   // row i has only bits j>i
        alive &= ~row;
        m = (i == 63) ? 0ULL : (alive & (~0ULL << (i + 1)));
      }
      if (t == 0) keepW[g] = keep;
    }
    __syncthreads();
    {
      u64 kw = keepW[g];
      int w = t & 15;
      if (w > g) {
        int i0 = (t >> 4) * 4;
        u64 acc = 0;
        for (int i = i0; i < i0 + 4; i++)
          if ((kw >> i) & 1ULL) acc |= rows[cur][i][w];
        if (acc) atomicOr(&remv[w], acc);
      }
    }
    if (g < 15) {
      u64* dstb = &rows[cur ^ 1][0][0];
      dstb[t] = pf0;
      dstb[t + 256] = pf1;
      dstb[t + 512] = pf2;
      dstb[t + 768] = pf3;
    }
    __syncthreads();   // remv + next buffer visible
  }
  const float* bb = boxF + (size_t)b * KTOP * 4;
  const float* sc = scoreF + (size_t)b * KTOP;
  for (int i = t; i < KTOP; i += 256) {
    float kf = ((keepW[i >> 6] >> (i & 63)) & 1ULL) ? 1.0f : 0.0f;
    size_t o5 = ((size_t)b * KTOP + i) * 5;
    out[o5 + 0] = bb[i * 4 + 0] * kf;
    out[o5 + 1] = bb[i * 4 + 1] * kf;
    out[o5 + 2] = bb[i * 4 + 2] * kf;
    out[o5 + 3] = bb[i * 4 + 3] * kf;
    out[o5 + 4] = sc[i] * kf;
    out[(size_t)BATCH * KTOP * 5 + (size_t)b * KTOP + i] = kf;
  }
}

extern "C" void kernel_launch(void* const* d_in, const int* in_sizes, int n_in,
                              void* d_out, int out_size, void* d_ws, size_t ws_size,
                              hipStream_t stream) {
  const float* locs = nullptr;
  const float* confs = nullptr;
  const float* priors = nullptr;
  for (int i = 0; i < n_in; i++) {
    if (in_sizes[i] == BATCH * NPRI * 4) locs = (const float*)d_in[i];
    else if (in_sizes[i] == BATCH * NPRI * 2) confs = (const float*)d_in[i];
    else if (in_sizes[i] == NPRI * 4) priors = (const float*)d_in[i];
  }
  float* out = (float*)d_out;   // f32: [B,K,5] dets ++ [B,K] keep

  char* ws = (char*)d_ws;
  size_t off = 0;
  u64* sup = (u64*)(ws + off);           off += (size_t)BATCH * KTOP * 16 * 8;  // 8,388,608
  u32* hist = (u32*)(ws + off);          off += (size_t)BATCH * NBIN * 4;       // 4,194,304
  u16* binG = (u16*)(ws + off);          off += (size_t)BATCH * NPRI * 2;       // 2,752,512
  float* boxF = (float*)(ws + off);      off += (size_t)BATCH * KTOP * 4 * 4;   // 1,048,576
  float* scoreF = (float*)(ws + off);    off += (size_t)BATCH * KTOP * 4;       //   262,144
  u64* validW = (u64*)(ws + off);        off += (size_t)BATCH * 16 * 8;         //     8,192
  // total ~16.7 MB

  const int histN = BATCH * NBIN;
  k_zero<<<(histN + 255) / 256, 256, 0, stream>>>(hist, histN);
  k_hist<<<(BATCH * NPRI) / 256, 256, 0, stream>>>(confs, binG, hist);
  k_sel<<<BATCH, 256, 0, stream>>>(binG, hist, confs, locs, priors, boxF, scoreF, validW);
  k_iou<<<dim3(16, BATCH), 256, 0, stream>>>(boxF, sup);
  k_scan<<<BATCH, 256, 0, stream>>>(sup, validW, boxF, scoreF, out);
}